// Round 7
// baseline (193.045 us; speedup 1.0000x reference)
//
#include <hip/hip_runtime.h>
#include <hip/hip_bf16.h>
#include <math.h>

// ---------------------------------------------------------------------------
// CrossModalityMultiHeadAttention  (MI355X / gfx950)
// Round 14: weight transposes moved INLINE into GEMM B-staging.
// R13 (184.0us, best): fold fixed, fused_prep left the top-5. Remaining
// addressable fat: D1's 5 transpose z-planes (320 blocks + ~10MB traffic)
// whose only consumer is GEMM staging. R13's fold_tile proved both staging
// primitives (natural cast + 4x4 reg-transpose into the swizzled fragment
// layout), so tail-qkv and out-proj GEMMs now read fp32 weights directly,
// transposing during LDS staging (2-barrier reg-prefetch skeleton, fold-
// identical). q2T..d2T eliminated.
//   D1: act casts + ranges + fold(Fq,Fk,Fv)         (512,1,3)
//   D2: 6 qkv GEMMs  head: A=hh_bf,B=F(bf16) | tail: A=ht_bf,B=w2(fp32T)
//   D3: attention (verbatim)
//   D4: out-proj     A=ctx(bf16), B=d_w(fp32T)
// ---------------------------------------------------------------------------

typedef __bf16 bf16x8 __attribute__((ext_vector_type(8)));
typedef __bf16 bf16x4 __attribute__((ext_vector_type(4)));
typedef float  f32x4  __attribute__((ext_vector_type(4)));

#define HID 512
#define NTOK 4096

// ------------------------------ fold tile ----------------------------------
// F[n][k] = sum_j Wf[j][n] * Mrow(k)[j],  Mrow(k) = map_w[k] (k<300),
// map_b (k==300), 0 (k>300).  Register-prefetched fp32 staging.
// (verbatim from round 13 -- passed, absmax 0.03125)
__device__ __forceinline__ void fold_tile(
    const float* __restrict__ Wf,   // [512][512] fp32
    const float* __restrict__ Mw,   // [300][512] fp32
    const float* __restrict__ Mb,   // [512] fp32
    __bf16* __restrict__ F,         // [512][320] bf16 out
    int bx, int by, char* SMEM)
{
    __bf16* As = (__bf16*)SMEM;            // [128][32]
    __bf16* Bs = (__bf16*)(SMEM + 8192);   // [128][32]

    const int tid  = threadIdx.x;
    const int wave = tid >> 6;
    const int lane = tid & 63;
    const int quad = lane >> 4;
    const int l16  = lane & 15;
    const int wy   = wave >> 1;
    const int wx   = wave & 1;
    const int rowBase = by * 128;   // n
    const int colBase = bx * 128;   // k

    const int s_row = tid >> 2;
    const int s_gc  = (tid & 3) ^ ((s_row >> 1) & 3);   // global j-chunk
    const int a_j4 = (tid & 7) * 4;     // j-offset within 32-step
    const int a_n4 = (tid >> 3) * 4;    // n-offset within 128

    float aR[16];
    float4 b0lo, b0hi, b1lo, b1hi;

    auto loadA = [&](int j0) {
        #pragma unroll
        for (int u = 0; u < 4; ++u)
            *(float4*)&aR[u * 4] =
                *(const float4*)&Wf[(size_t)(j0 + a_j4 + u) * 512 + rowBase + a_n4];
    };
    auto loadRow = [&](int k, int jc, float4& lo, float4& hi) {
        if (k < 300) {
            lo = *(const float4*)&Mw[(size_t)k * 512 + jc];
            hi = *(const float4*)&Mw[(size_t)k * 512 + jc + 4];
        } else if (k == 300) {
            lo = *(const float4*)&Mb[jc];
            hi = *(const float4*)&Mb[jc + 4];
        } else {
            lo = float4{0.f, 0.f, 0.f, 0.f};
            hi = float4{0.f, 0.f, 0.f, 0.f};
        }
    };
    auto loadB = [&](int j0) {
        const int jc = j0 + s_gc * 8;
        loadRow(colBase + s_row,      jc, b0lo, b0hi);
        loadRow(colBase + 64 + s_row, jc, b1lo, b1hi);
    };

    f32x4 acc[4][4] = {};

    loadA(0);
    loadB(0);

    for (int i = 0; i < 16; ++i) {
        __syncthreads();   // previous MFMA done reading LDS
        #pragma unroll
        for (int v = 0; v < 4; ++v) {
            const int r = a_n4 + v;
            const int p = (a_j4 >> 3) ^ ((r >> 1) & 3);
            bf16x4 w;
            w[0] = (__bf16)aR[0 * 4 + v];
            w[1] = (__bf16)aR[1 * 4 + v];
            w[2] = (__bf16)aR[2 * 4 + v];
            w[3] = (__bf16)aR[3 * 4 + v];
            *(bf16x4*)&As[r * 32 + p * 8 + (a_j4 & 7)] = w;
        }
        {
            bf16x8 v0, v1;
            v0[0]=(__bf16)b0lo.x; v0[1]=(__bf16)b0lo.y; v0[2]=(__bf16)b0lo.z; v0[3]=(__bf16)b0lo.w;
            v0[4]=(__bf16)b0hi.x; v0[5]=(__bf16)b0hi.y; v0[6]=(__bf16)b0hi.z; v0[7]=(__bf16)b0hi.w;
            v1[0]=(__bf16)b1lo.x; v1[1]=(__bf16)b1lo.y; v1[2]=(__bf16)b1lo.z; v1[3]=(__bf16)b1lo.w;
            v1[4]=(__bf16)b1hi.x; v1[5]=(__bf16)b1hi.y; v1[6]=(__bf16)b1hi.z; v1[7]=(__bf16)b1hi.w;
            *(bf16x8*)&Bs[tid * 8]        = v0;
            *(bf16x8*)&Bs[2048 + tid * 8] = v1;
        }
        if (i + 1 < 16) { loadA((i + 1) * 32); loadB((i + 1) * 32); }
        __syncthreads();   // LDS writes visible

        bf16x8 ar[4], br[4];
        #pragma unroll
        for (int ii = 0; ii < 4; ++ii) {
            const int ra = wy * 64 + ii * 16 + l16;
            ar[ii] = *(const bf16x8*)&As[ra * 32 + ((quad ^ ((ra >> 1) & 3)) << 3)];
        }
        #pragma unroll
        for (int jj = 0; jj < 4; ++jj) {
            const int rb = wx * 64 + jj * 16 + l16;
            br[jj] = *(const bf16x8*)&Bs[rb * 32 + ((quad ^ ((rb >> 1) & 3)) << 3)];
        }
        #pragma unroll
        for (int ii = 0; ii < 4; ++ii)
            #pragma unroll
            for (int jj = 0; jj < 4; ++jj)
                acc[ii][jj] = __builtin_amdgcn_mfma_f32_16x16x32_bf16(ar[ii], br[jj], acc[ii][jj], 0, 0, 0);
    }

    #pragma unroll
    for (int jj = 0; jj < 4; ++jj) {
        int col = colBase + wx * 64 + jj * 16 + l16;
        if (col < 320) {
            #pragma unroll
            for (int ii = 0; ii < 4; ++ii) {
                #pragma unroll
                for (int r = 0; r < 4; ++r) {
                    int row = rowBase + wy * 64 + ii * 16 + quad * 4 + r;
                    F[(size_t)row * 320 + col] = (__bf16)acc[ii][jj][r];
                }
            }
        }
    }
}

// ----------------------------- fused prep ----------------------------------
// grid (512, 1, 3):
//   z=0 : h_head fp32 -> hh_bf [4096][320] (col300=1.0, 301..319=0) + ranges
//   z=1 : h_tail fp32 -> ht_bf [4096][512]
//   z=2 : q<36 : fold tiles (f = q/12, tile = q%12)
struct PrepArgs {
    const float* h_head; const float* h_tail;
    const int* bh; const int* bt;
    const float* map_w; const float* map_b;
    const float* qkvw[3];                         // q1,k1,v1 fp32
    __bf16* hh_bf; __bf16* ht_bf;
    __bf16* F[3];
    int* ranges;
};

__global__ __launch_bounds__(256) void fused_prep(PrepArgs pa) {
    const int q = blockIdx.x, z = blockIdx.z, tid = threadIdx.x;
    __shared__ __align__(16) char SMEM[16384];

    if (z == 0) {
        if (q == 0 && tid < 128) {
            int b = tid & 63;
            const int* arr = (tid < 64) ? pa.bh : pa.bt;
            int base = (tid < 64) ? 0 : 128;
            int lo = 0, hi = NTOK;
            while (lo < hi) { int mid = (lo + hi) >> 1; if (arr[mid] < b) lo = mid + 1; else hi = mid; }
            int start = lo;
            lo = 0; hi = NTOK;
            while (lo < hi) { int mid = (lo + hi) >> 1; if (arr[mid] <= b) lo = mid + 1; else hi = mid; }
            pa.ranges[base + b] = start;
            pa.ranges[base + 64 + b] = lo;
        }
        for (int idx = tid; idx < 8 * 40; idx += 256) {
            int r   = q * 8 + idx / 40;
            int col = (idx % 40) * 8;
            bf16x8 v;
            if (col + 8 <= 300) {
                float4 f0 = *(const float4*)&pa.h_head[(size_t)r * 300 + col];
                float4 f1 = *(const float4*)&pa.h_head[(size_t)r * 300 + col + 4];
                v[0]=(__bf16)f0.x; v[1]=(__bf16)f0.y; v[2]=(__bf16)f0.z; v[3]=(__bf16)f0.w;
                v[4]=(__bf16)f1.x; v[5]=(__bf16)f1.y; v[6]=(__bf16)f1.z; v[7]=(__bf16)f1.w;
            } else if (col < 300) {  // col == 296: 4 valid + one(k=300) + pad
                float4 f0 = *(const float4*)&pa.h_head[(size_t)r * 300 + col];
                v[0]=(__bf16)f0.x; v[1]=(__bf16)f0.y; v[2]=(__bf16)f0.z; v[3]=(__bf16)f0.w;
                v[4]=(__bf16)1.0f;  // col 300: constant-1 column (bias fold)
                v[5]=(__bf16)0.f; v[6]=(__bf16)0.f; v[7]=(__bf16)0.f;
            } else {
                #pragma unroll
                for (int j = 0; j < 8; ++j) v[j] = (__bf16)0.f;
            }
            *(bf16x8*)&pa.hh_bf[(size_t)r * 320 + col] = v;
        }
    } else if (z == 1) {
        for (int idx = tid; idx < 8 * 64; idx += 256) {
            int r   = q * 8 + (idx >> 6);
            int col = (idx & 63) * 8;
            float4 f0 = *(const float4*)&pa.h_tail[(size_t)r * 512 + col];
            float4 f1 = *(const float4*)&pa.h_tail[(size_t)r * 512 + col + 4];
            bf16x8 v;
            v[0]=(__bf16)f0.x; v[1]=(__bf16)f0.y; v[2]=(__bf16)f0.z; v[3]=(__bf16)f0.w;
            v[4]=(__bf16)f1.x; v[5]=(__bf16)f1.y; v[6]=(__bf16)f1.z; v[7]=(__bf16)f1.w;
            *(bf16x8*)&pa.ht_bf[(size_t)r * 512 + col] = v;
        }
    } else {
        if (q >= 36) return;
        const int f = q / 12, t = q % 12;
        fold_tile(pa.qkvw[f], pa.map_w, pa.map_b, pa.F[f], t % 3, t / 3, SMEM);
    }
}

// ------------------------ reg-staged GEMM 128x128 --------------------------
// C[row][col] = sum_k A[row][k] * BT[col][k] + bias[col]
// A: bf16 [M][Ald] natural-staged. B: either bf16 [N][Bld] natural-staged
// (folded F) or fp32 [K][N] transpose-staged in-register (raw weights).
// 2-barrier reg-prefetch skeleton identical to fold_tile (proven R13).
struct RSJobs {
    const __bf16* A[6];   int Ald[6];
    const void*   B[6];   int Bld[6];  int Bf32t[6];
    const float*  bias[6];
    void*         C[6];
    int           Kp[6];
};

template <typename TC>
__global__ __launch_bounds__(256) void gemm_rs(RSJobs jb) {
    __shared__ __align__(16) __bf16 As[4096];   // [128][32]
    __shared__ __align__(16) __bf16 Bs[4096];

    const int z = blockIdx.z;
    const __bf16* A    = jb.A[z];
    const int     Ald  = jb.Ald[z];
    const int     f32t = jb.Bf32t[z];
    const float*  Bf   = (const float*)jb.B[z];
    const __bf16* Bb   = (const __bf16*)jb.B[z];
    const int     Bld  = jb.Bld[z];
    const float*  bias = jb.bias[z];
    TC*           C    = (TC*)jb.C[z];
    const int     Kp   = jb.Kp[z];

    const int tid  = threadIdx.x;
    const int wave = tid >> 6;
    const int lane = tid & 63;
    const int quad = lane >> 4;
    const int l16  = lane & 15;
    const int wy   = wave >> 1;
    const int wx   = wave & 1;
    const int rowBase = blockIdx.y * 128;
    const int colBase = blockIdx.x * 128;

    // natural staging (matches gload_lds slot map: slot tid*8, src chunk swz)
    const int n_row = tid >> 2;
    const int n_off = ((tid & 3) ^ ((n_row >> 1) & 3)) * 8;
    // transpose staging (fold A-pattern)
    const int t_j4 = (tid & 7) * 4;     // k-offset within 32-step
    const int t_n4 = (tid >> 3) * 4;    // col-offset within 128

    bf16x8 aR[2];
    bf16x8 bRb[2];
    float  bRf[16];

    auto loadT = [&](int k0) {
        #pragma unroll
        for (int h = 0; h < 2; ++h)
            aR[h] = *(const bf16x8*)&A[(size_t)(rowBase + n_row + 64 * h) * Ald + k0 + n_off];
        if (f32t) {
            #pragma unroll
            for (int u = 0; u < 4; ++u)
                *(float4*)&bRf[u * 4] =
                    *(const float4*)&Bf[(size_t)(k0 + t_j4 + u) * Bld + colBase + t_n4];
        } else {
            #pragma unroll
            for (int h = 0; h < 2; ++h)
                bRb[h] = *(const bf16x8*)&Bb[(size_t)(colBase + n_row + 64 * h) * Bld + k0 + n_off];
        }
    };

    f32x4 acc[4][4] = {};
    const int nk = Kp >> 5;

    loadT(0);

    for (int i = 0; i < nk; ++i) {
        __syncthreads();   // previous MFMA done reading LDS
        #pragma unroll
        for (int h = 0; h < 2; ++h)
            *(bf16x8*)&As[h * 2048 + tid * 8] = aR[h];
        if (f32t) {
            #pragma unroll
            for (int v = 0; v < 4; ++v) {
                const int r = t_n4 + v;
                const int p = (t_j4 >> 3) ^ ((r >> 1) & 3);
                bf16x4 w;
                w[0] = (__bf16)bRf[0 * 4 + v];
                w[1] = (__bf16)bRf[1 * 4 + v];
                w[2] = (__bf16)bRf[2 * 4 + v];
                w[3] = (__bf16)bRf[3 * 4 + v];
                *(bf16x4*)&Bs[r * 32 + p * 8 + (t_j4 & 7)] = w;
            }
        } else {
            #pragma unroll
            for (int h = 0; h < 2; ++h)
                *(bf16x8*)&Bs[h * 2048 + tid * 8] = bRb[h];
        }
        if (i + 1 < nk) loadT((i + 1) * 32);   // prefetch flies over MFMA
        __syncthreads();   // LDS writes visible

        bf16x8 ar[4], br[4];
        #pragma unroll
        for (int ii = 0; ii < 4; ++ii) {
            const int ra = wy * 64 + ii * 16 + l16;
            ar[ii] = *(const bf16x8*)&As[ra * 32 + ((quad ^ ((ra >> 1) & 3)) << 3)];
        }
        #pragma unroll
        for (int jj = 0; jj < 4; ++jj) {
            const int rb = wx * 64 + jj * 16 + l16;
            br[jj] = *(const bf16x8*)&Bs[rb * 32 + ((quad ^ ((rb >> 1) & 3)) << 3)];
        }
        #pragma unroll
        for (int ii = 0; ii < 4; ++ii)
            #pragma unroll
            for (int jj = 0; jj < 4; ++jj)
                acc[ii][jj] = __builtin_amdgcn_mfma_f32_16x16x32_bf16(ar[ii], br[jj], acc[ii][jj], 0, 0, 0);
    }

    // epilogue: C/D layout col=l16, row=quad*4+reg
    #pragma unroll
    for (int jj = 0; jj < 4; ++jj) {
        int col = colBase + wx * 64 + jj * 16 + l16;
        float bv = bias[col];
        #pragma unroll
        for (int ii = 0; ii < 4; ++ii) {
            #pragma unroll
            for (int r = 0; r < 4; ++r) {
                int row = rowBase + wy * 64 + ii * 16 + quad * 4 + r;
                C[(size_t)row * HID + col] = (TC)(acc[ii][jj][r] + bv);
            }
        }
    }
}

// ------------------------- MFMA flash attention ----------------------------
// grid = (head 8, batch 64, side 2). side 0: head-q x tail-k; side 1: swap.
__global__ __launch_bounds__(256) void attn_mfma(
    const __bf16* __restrict__ Q0, const __bf16* __restrict__ K0,
    const __bf16* __restrict__ Vr0, const __bf16* __restrict__ Vc0,
    const __bf16* __restrict__ Q1, const __bf16* __restrict__ K1,
    const __bf16* __restrict__ Vr1, const __bf16* __restrict__ Vc1,
    const int* __restrict__ ranges,
    __bf16* __restrict__ O0, __bf16* __restrict__ O1,
    int Nq, int Nk)
{
    __shared__ __align__(16) __bf16 Qs[64][72];
    __shared__ __align__(16) __bf16 Ks[64][72];
    __shared__ __align__(16) __bf16 Vt[64][72];   // [dim][key]
    __shared__ __align__(16) __bf16 Ps[64][72];   // [query][key]

    const int z = blockIdx.z;
    const __bf16* Q    = z ? Q1 : Q0;
    const __bf16* Kg   = z ? K1 : K0;
    const __bf16* Vres = z ? Vr1 : Vr0;
    const __bf16* Vctx = z ? Vc1 : Vc0;
    __bf16* Out        = z ? O1 : O0;
    const int* qstart  = z ? ranges + 128 : ranges;
    const int* qend    = z ? ranges + 192 : ranges + 64;
    const int* kstart  = z ? ranges       : ranges + 128;
    const int* kend    = z ? ranges + 64  : ranges + 192;

    const int h = blockIdx.x, b = blockIdx.y;
    const int qs = qstart[b], qe = qend[b];
    const int ts = kstart[b], te = kend[b];
    const int nq = qe - qs, nk = te - ts;
    if (nq <= 0) return;

    const int tid  = threadIdx.x;
    const int wave = tid >> 6;
    const int lane = tid & 63;
    const int quad = lane >> 4;
    const int l16  = lane & 15;
    const int srow = tid >> 2;
    const int scol = (tid & 3) * 16;

    if (nk <= 0) {
        float* meanv = (float*)Qs;
        if (tid < 64) {
            float s = 0.f;
            for (int m = 0; m < Nk; ++m)
                s += (float)Vctx[(size_t)m * HID + h * 64 + tid];
            meanv[tid] = s / (float)Nk;
        }
        __syncthreads();
        int d = tid & 63;
        for (int r = qs + (tid >> 6); r < qe; r += 4) {
            size_t off = (size_t)r * HID + h * 64 + d;
            Out[off] = (__bf16)((float)Vres[off] + meanv[d]);
        }
        return;
    }

    for (int qc = 0; qc < nq; qc += 64) {
        __syncthreads();
        {
            int qg = min(qs + qc + srow, Nq - 1);
            const __bf16* src = Q + (size_t)qg * HID + h * 64 + scol;
            *(bf16x8*)&Qs[srow][scol]     = *(const bf16x8*)src;
            *(bf16x8*)&Qs[srow][scol + 8] = *(const bf16x8*)(src + 8);
        }
        __syncthreads();
        bf16x8 aq0 = *(const bf16x8*)&Qs[wave * 16 + l16][quad * 8];
        bf16x8 aq1 = *(const bf16x8*)&Qs[wave * 16 + l16][32 + quad * 8];

        f32x4 O[4] = {};
        float Mx[4], L[4];
        #pragma unroll
        for (int r = 0; r < 4; ++r) { Mx[r] = -__builtin_inff(); L[r] = 0.f; }

        for (int kc = 0; kc < nk; kc += 64) {
            __syncthreads();
            {
                int kg = min(ts + kc + srow, Nk - 1);
                const __bf16* ksrc = Kg + (size_t)kg * HID + h * 64 + scol;
                *(bf16x8*)&Ks[srow][scol]     = *(const bf16x8*)ksrc;
                *(bf16x8*)&Ks[srow][scol + 8] = *(const bf16x8*)(ksrc + 8);
                const __bf16* vsrc = Vctx + (size_t)kg * HID + h * 64 + scol;
                bf16x8 v0 = *(const bf16x8*)vsrc;
                bf16x8 v1 = *(const bf16x8*)(vsrc + 8);
                #pragma unroll
                for (int j = 0; j < 8; ++j) {
                    Vt[scol + j][srow]     = v0[j];
                    Vt[scol + 8 + j][srow] = v1[j];
                }
            }
            __syncthreads();

            f32x4 S[4] = {};
            #pragma unroll
            for (int c = 0; c < 4; ++c) {
                bf16x8 bk0 = *(const bf16x8*)&Ks[c * 16 + l16][quad * 8];
                bf16x8 bk1 = *(const bf16x8*)&Ks[c * 16 + l16][32 + quad * 8];
                S[c] = __builtin_amdgcn_mfma_f32_16x16x32_bf16(aq0, bk0, S[c], 0, 0, 0);
                S[c] = __builtin_amdgcn_mfma_f32_16x16x32_bf16(aq1, bk1, S[c], 0, 0, 0);
            }

            #pragma unroll
            for (int c = 0; c < 4; ++c) {
                bool valid = (ts + kc + c * 16 + l16) < te;
                #pragma unroll
                for (int r = 0; r < 4; ++r)
                    S[c][r] = valid ? S[c][r] * 0.125f : -__builtin_inff();
            }

            float cm[4], ps[4], alpha[4];
            #pragma unroll
            for (int r = 0; r < 4; ++r) {
                float v = fmaxf(fmaxf(S[0][r], S[1][r]), fmaxf(S[2][r], S[3][r]));
                v = fmaxf(v, __shfl_xor(v, 1, 64));
                v = fmaxf(v, __shfl_xor(v, 2, 64));
                v = fmaxf(v, __shfl_xor(v, 4, 64));
                v = fmaxf(v, __shfl_xor(v, 8, 64));
                cm[r] = v;
            }
            #pragma unroll
            for (int r = 0; r < 4; ++r) {
                float nM = fmaxf(Mx[r], cm[r]);
                alpha[r] = __expf(Mx[r] - nM);
                Mx[r] = nM;
                ps[r] = 0.f;
            }
            #pragma unroll
            for (int c = 0; c < 4; ++c)
                #pragma unroll
                for (int r = 0; r < 4; ++r) {
                    float p = __expf(S[c][r] - Mx[r]);
                    S[c][r] = p;
                    ps[r] += p;
                }
            #pragma unroll
            for (int r = 0; r < 4; ++r) {
                float v = ps[r];
                v += __shfl_xor(v, 1, 64);
                v += __shfl_xor(v, 2, 64);
                v += __shfl_xor(v, 4, 64);
                v += __shfl_xor(v, 8, 64);
                L[r] = L[r] * alpha[r] + v;
            }
            #pragma unroll
            for (int c = 0; c < 4; ++c)
                #pragma unroll
                for (int r = 0; r < 4; ++r)
                    O[c][r] *= alpha[r];

            #pragma unroll
            for (int c = 0; c < 4; ++c)
                #pragma unroll
                for (int r = 0; r < 4; ++r)
                    Ps[wave * 16 + quad * 4 + r][c * 16 + l16] = (__bf16)S[c][r];
            __syncthreads();

            bf16x8 ap0 = *(const bf16x8*)&Ps[wave * 16 + l16][quad * 8];
            bf16x8 ap1 = *(const bf16x8*)&Ps[wave * 16 + l16][32 + quad * 8];
            #pragma unroll
            for (int c = 0; c < 4; ++c) {
                bf16x8 bv0 = *(const bf16x8*)&Vt[c * 16 + l16][quad * 8];
                bf16x8 bv1 = *(const bf16x8*)&Vt[c * 16 + l16][32 + quad * 8];
                O[c] = __builtin_amdgcn_mfma_f32_16x16x32_bf16(ap0, bv0, O[c], 0, 0, 0);
                O[c] = __builtin_amdgcn_mfma_f32_16x16x32_bf16(ap1, bv1, O[c], 0, 0, 0);
            }
        }

        #pragma unroll
        for (int c = 0; c < 4; ++c) {
            int d = h * 64 + c * 16 + l16;
            #pragma unroll
            for (int r = 0; r < 4; ++r) {
                int qrow = qs + qc + wave * 16 + quad * 4 + r;
                if (qrow < qe) {
                    size_t off = (size_t)qrow * HID + d;
                    Out[off] = (__bf16)((float)Vres[off] + O[c][r] / L[r]);
                }
            }
        }
    }
}

// ------------------------------ launcher -----------------------------------
extern "C" void kernel_launch(void* const* d_in, const int* in_sizes, int n_in,
                              void* d_out, int out_size, void* d_ws, size_t ws_size,
                              hipStream_t stream) {
    (void)in_sizes; (void)n_in; (void)out_size; (void)ws_size;

    const float* h_head = (const float*)d_in[0];
    const float* h_tail = (const float*)d_in[1];
    const int* batch_head = (const int*)d_in[2];
    const int* batch_tail = (const int*)d_in[3];
    const float* map_w = (const float*)d_in[4];
    const float* map_b = (const float*)d_in[5];
    const float* q1_w = (const float*)d_in[6];
    const float* q1_b = (const float*)d_in[7];
    const float* k1_w = (const float*)d_in[8];
    const float* k1_b = (const float*)d_in[9];
    const float* v1_w = (const float*)d_in[10];
    const float* v1_b = (const float*)d_in[11];
    const float* q2_w = (const float*)d_in[12];
    const float* q2_b = (const float*)d_in[13];
    const float* k2_w = (const float*)d_in[14];
    const float* k2_b = (const float*)d_in[15];
    const float* v2_w = (const float*)d_in[16];
    const float* v2_b = (const float*)d_in[17];
    const float* d1_w = (const float*)d_in[18];
    const float* d1_b = (const float*)d_in[19];
    const float* d2_w = (const float*)d_in[20];
    const float* d2_b = (const float*)d_in[21];

    float* out = (float*)d_out;

    const size_t SZ = (size_t)NTOK * HID;
    char* ws = (char*)d_ws;
    int* ranges   = (int*)ws;                            // 1 KB
    __bf16* hh_bf = (__bf16*)(ws + 1024);                // [4096][320]
    __bf16* ht_bf = hh_bf + (size_t)NTOK * 320;          // [4096][512]
    __bf16* FqT  = ht_bf + SZ;                           // [512][320] each
    __bf16* FkT  = FqT + 512 * 320;
    __bf16* FvT  = FkT + 512 * 320;
    __bf16* qh   = FvT + 512 * 320;                      // [4096][512] each
    __bf16* kh   = qh  + SZ;
    __bf16* vh   = kh  + SZ;
    __bf16* qt   = vh  + SZ;
    __bf16* kt   = qt  + SZ;
    __bf16* vt   = kt  + SZ;
    __bf16* ctxh = vt  + SZ;
    __bf16* ctxt = ctxh + SZ;

    // D1: casts + ranges + fold (transposes now inline in GEMM staging)
    PrepArgs pa;
    pa.h_head = h_head; pa.h_tail = h_tail;
    pa.bh = batch_head; pa.bt = batch_tail;
    pa.map_w = map_w; pa.map_b = map_b;
    pa.qkvw[0] = q1_w; pa.qkvw[1] = k1_w; pa.qkvw[2] = v1_w;
    pa.hh_bf = hh_bf; pa.ht_bf = ht_bf;
    pa.F[0] = FqT; pa.F[1] = FkT; pa.F[2] = FvT;
    pa.ranges = ranges;
    fused_prep<<<dim3(512, 1, 3), dim3(256), 0, stream>>>(pa);

    // D2: 6 qkv GEMMs (head: B = folded F bf16; tail: B = raw fp32 w, inline-T)
    {
        RSJobs j;
        j.A[0] = hh_bf; j.Ald[0] = 320; j.B[0] = FqT;  j.Bld[0] = 320; j.Bf32t[0] = 0;
        j.bias[0] = q1_b; j.C[0] = qh; j.Kp[0] = 320;
        j.A[1] = hh_bf; j.Ald[1] = 320; j.B[1] = FkT;  j.Bld[1] = 320; j.Bf32t[1] = 0;
        j.bias[1] = k1_b; j.C[1] = kh; j.Kp[1] = 320;
        j.A[2] = hh_bf; j.Ald[2] = 320; j.B[2] = FvT;  j.Bld[2] = 320; j.Bf32t[2] = 0;
        j.bias[2] = v1_b; j.C[2] = vh; j.Kp[2] = 320;
        j.A[3] = ht_bf; j.Ald[3] = 512; j.B[3] = q2_w; j.Bld[3] = 512; j.Bf32t[3] = 1;
        j.bias[3] = q2_b; j.C[3] = qt; j.Kp[3] = 512;
        j.A[4] = ht_bf; j.Ald[4] = 512; j.B[4] = k2_w; j.Bld[4] = 512; j.Bf32t[4] = 1;
        j.bias[4] = k2_b; j.C[4] = kt; j.Kp[4] = 512;
        j.A[5] = ht_bf; j.Ald[5] = 512; j.B[5] = v2_w; j.Bld[5] = 512; j.Bf32t[5] = 1;
        j.bias[5] = v2_b; j.C[5] = vt; j.Kp[5] = 512;
        gemm_rs<__bf16><<<dim3(4, 32, 6), dim3(256), 0, stream>>>(j);
    }

    // D3: attention (both sides, one dispatch)
    attn_mfma<<<dim3(8, 64, 2), dim3(256), 0, stream>>>(
        qh, kt, vh, vt,
        qt, kh, vt, vh,
        ranges, ctxh, ctxt, NTOK, NTOK);

    // D4: output projections (fp32 into d_out; B = raw fp32 d_w, inline-T)
    {
        RSJobs j;
        for (int i = 0; i < 6; ++i) {
            int s = (i < 2) ? i : 1;
            j.A[i] = s ? ctxt : ctxh; j.Ald[i] = 512;
            j.B[i] = s ? (const void*)d2_w : (const void*)d1_w;
            j.Bld[i] = 512; j.Bf32t[i] = 1;
            j.bias[i] = s ? d2_b : d1_b;
            j.C[i] = s ? (void*)(out + SZ) : (void*)out;
            j.Kp[i] = 512;
        }
        gemm_rs<float><<<dim3(4, 32, 2), dim3(256), 0, stream>>>(j);
    }
}

// Round 8
// 185.567 us; speedup vs baseline: 1.0403x; 1.0403x over previous
//
#include <hip/hip_runtime.h>
#include <hip/hip_bf16.h>
#include <math.h>

// ---------------------------------------------------------------------------
// CrossModalityMultiHeadAttention  (MI355X / gfx950)
// Round 15: REVERT to round-13 (184.0us, session best) after R14's inline-
// transpose reg-staged GEMM regressed (+9us: global_load_lds double-buffer
// beats reg-staging per 128^2 job -- matches learn_hip m151). Single safe
// tweak kept: fused_prep grid flattened (512,1,8)->(1380) to drop ~2700
// empty early-return blocks.
// Graph: D1 prep(casts+ranges+5 transposes+fold) -> D2 all-6 qkv ->
//        D3 attn -> D4 out-proj.  All bodies byte-identical to R13.
// ---------------------------------------------------------------------------

typedef __bf16 bf16x8 __attribute__((ext_vector_type(8)));
typedef __bf16 bf16x4 __attribute__((ext_vector_type(4)));
typedef float  f32x4  __attribute__((ext_vector_type(4)));

#define HID 512
#define NTOK 4096

#define AS1(p) ((const __attribute__((address_space(1))) void*)(p))
#define AS3(p) ((__attribute__((address_space(3))) void*)(p))

// ------------------------------ fold tile ----------------------------------
// F[n][k] = sum_j Wf[j][n] * Mrow(k)[j],  Mrow(k) = map_w[k] (k<300),
// map_b (k==300), 0 (k>300).  Register-prefetched fp32 staging.
__device__ __forceinline__ void fold_tile(
    const float* __restrict__ Wf,   // [512][512] fp32
    const float* __restrict__ Mw,   // [300][512] fp32
    const float* __restrict__ Mb,   // [512] fp32
    __bf16* __restrict__ F,         // [512][320] bf16 out
    int bx, int by, char* SMEM)
{
    __bf16* As = (__bf16*)SMEM;            // [128][32]
    __bf16* Bs = (__bf16*)(SMEM + 8192);   // [128][32]

    const int tid  = threadIdx.x;
    const int wave = tid >> 6;
    const int lane = tid & 63;
    const int quad = lane >> 4;
    const int l16  = lane & 15;
    const int wy   = wave >> 1;
    const int wx   = wave & 1;
    const int rowBase = by * 128;   // n
    const int colBase = bx * 128;   // k

    const int s_row = tid >> 2;
    const int s_gc  = (tid & 3) ^ ((s_row >> 1) & 3);   // global j-chunk
    const int a_j4 = (tid & 7) * 4;     // j-offset within 32-step
    const int a_n4 = (tid >> 3) * 4;    // n-offset within 128

    float aR[16];
    float4 b0lo, b0hi, b1lo, b1hi;

    auto loadA = [&](int j0) {
        #pragma unroll
        for (int u = 0; u < 4; ++u)
            *(float4*)&aR[u * 4] =
                *(const float4*)&Wf[(size_t)(j0 + a_j4 + u) * 512 + rowBase + a_n4];
    };
    auto loadRow = [&](int k, int jc, float4& lo, float4& hi) {
        if (k < 300) {
            lo = *(const float4*)&Mw[(size_t)k * 512 + jc];
            hi = *(const float4*)&Mw[(size_t)k * 512 + jc + 4];
        } else if (k == 300) {
            lo = *(const float4*)&Mb[jc];
            hi = *(const float4*)&Mb[jc + 4];
        } else {
            lo = float4{0.f, 0.f, 0.f, 0.f};
            hi = float4{0.f, 0.f, 0.f, 0.f};
        }
    };
    auto loadB = [&](int j0) {
        const int jc = j0 + s_gc * 8;
        loadRow(colBase + s_row,      jc, b0lo, b0hi);
        loadRow(colBase + 64 + s_row, jc, b1lo, b1hi);
    };

    f32x4 acc[4][4] = {};

    loadA(0);
    loadB(0);

    for (int i = 0; i < 16; ++i) {
        __syncthreads();   // previous MFMA done reading LDS
        #pragma unroll
        for (int v = 0; v < 4; ++v) {
            const int r = a_n4 + v;
            const int p = (a_j4 >> 3) ^ ((r >> 1) & 3);
            bf16x4 w;
            w[0] = (__bf16)aR[0 * 4 + v];
            w[1] = (__bf16)aR[1 * 4 + v];
            w[2] = (__bf16)aR[2 * 4 + v];
            w[3] = (__bf16)aR[3 * 4 + v];
            *(bf16x4*)&As[r * 32 + p * 8 + (a_j4 & 7)] = w;
        }
        {
            bf16x8 v0, v1;
            v0[0]=(__bf16)b0lo.x; v0[1]=(__bf16)b0lo.y; v0[2]=(__bf16)b0lo.z; v0[3]=(__bf16)b0lo.w;
            v0[4]=(__bf16)b0hi.x; v0[5]=(__bf16)b0hi.y; v0[6]=(__bf16)b0hi.z; v0[7]=(__bf16)b0hi.w;
            v1[0]=(__bf16)b1lo.x; v1[1]=(__bf16)b1lo.y; v1[2]=(__bf16)b1lo.z; v1[3]=(__bf16)b1lo.w;
            v1[4]=(__bf16)b1hi.x; v1[5]=(__bf16)b1hi.y; v1[6]=(__bf16)b1hi.z; v1[7]=(__bf16)b1hi.w;
            *(bf16x8*)&Bs[tid * 8]        = v0;
            *(bf16x8*)&Bs[2048 + tid * 8] = v1;
        }
        if (i + 1 < 16) { loadA((i + 1) * 32); loadB((i + 1) * 32); }
        __syncthreads();   // LDS writes visible

        bf16x8 ar[4], br[4];
        #pragma unroll
        for (int ii = 0; ii < 4; ++ii) {
            const int ra = wy * 64 + ii * 16 + l16;
            ar[ii] = *(const bf16x8*)&As[ra * 32 + ((quad ^ ((ra >> 1) & 3)) << 3)];
        }
        #pragma unroll
        for (int jj = 0; jj < 4; ++jj) {
            const int rb = wx * 64 + jj * 16 + l16;
            br[jj] = *(const bf16x8*)&Bs[rb * 32 + ((quad ^ ((rb >> 1) & 3)) << 3)];
        }
        #pragma unroll
        for (int ii = 0; ii < 4; ++ii)
            #pragma unroll
            for (int jj = 0; jj < 4; ++jj)
                acc[ii][jj] = __builtin_amdgcn_mfma_f32_16x16x32_bf16(ar[ii], br[jj], acc[ii][jj], 0, 0, 0);
    }

    #pragma unroll
    for (int jj = 0; jj < 4; ++jj) {
        int col = colBase + wx * 64 + jj * 16 + l16;
        if (col < 320) {
            #pragma unroll
            for (int ii = 0; ii < 4; ++ii) {
                #pragma unroll
                for (int r = 0; r < 4; ++r) {
                    int row = rowBase + wy * 64 + ii * 16 + quad * 4 + r;
                    F[(size_t)row * 320 + col] = (__bf16)acc[ii][jj][r];
                }
            }
        }
    }
}

// ----------------------------- fused prep ----------------------------------
// flat grid (1380):
//   vb <  512 : h_head fp32 -> hh_bf [4096][320] (col300=1.0) + ranges
//   vb < 1024 : h_tail fp32 -> ht_bf [4096][512]
//   vb < 1060 : fold tiles (f = i/12, tile = i%12)
//   vb < 1380 : weight transpose (q2,k2,v2,d1,d2), 64 tiles each
struct PrepArgs {
    const float* h_head; const float* h_tail;
    const int* bh; const int* bt;
    const float* map_w; const float* map_b;
    const float* qkvw[3];                         // q1,k1,v1 fp32
    const float* tsrc[5]; __bf16* tdst[5];        // q2,k2,v2,d1,d2
    __bf16* hh_bf; __bf16* ht_bf;
    __bf16* F[3];
    int* ranges;
};

__global__ __launch_bounds__(256) void fused_prep(PrepArgs pa) {
    const int vb = blockIdx.x, tid = threadIdx.x;
    __shared__ __align__(16) char SMEM[16384];

    if (vb < 512) {
        const int q = vb;
        if (q == 0 && tid < 128) {
            int b = tid & 63;
            const int* arr = (tid < 64) ? pa.bh : pa.bt;
            int base = (tid < 64) ? 0 : 128;
            int lo = 0, hi = NTOK;
            while (lo < hi) { int mid = (lo + hi) >> 1; if (arr[mid] < b) lo = mid + 1; else hi = mid; }
            int start = lo;
            lo = 0; hi = NTOK;
            while (lo < hi) { int mid = (lo + hi) >> 1; if (arr[mid] <= b) lo = mid + 1; else hi = mid; }
            pa.ranges[base + b] = start;
            pa.ranges[base + 64 + b] = lo;
        }
        for (int idx = tid; idx < 8 * 40; idx += 256) {
            int r   = q * 8 + idx / 40;
            int col = (idx % 40) * 8;
            bf16x8 v;
            if (col + 8 <= 300) {
                float4 f0 = *(const float4*)&pa.h_head[(size_t)r * 300 + col];
                float4 f1 = *(const float4*)&pa.h_head[(size_t)r * 300 + col + 4];
                v[0]=(__bf16)f0.x; v[1]=(__bf16)f0.y; v[2]=(__bf16)f0.z; v[3]=(__bf16)f0.w;
                v[4]=(__bf16)f1.x; v[5]=(__bf16)f1.y; v[6]=(__bf16)f1.z; v[7]=(__bf16)f1.w;
            } else if (col < 300) {  // col == 296: 4 valid + one(k=300) + pad
                float4 f0 = *(const float4*)&pa.h_head[(size_t)r * 300 + col];
                v[0]=(__bf16)f0.x; v[1]=(__bf16)f0.y; v[2]=(__bf16)f0.z; v[3]=(__bf16)f0.w;
                v[4]=(__bf16)1.0f;  // col 300: constant-1 column (bias fold)
                v[5]=(__bf16)0.f; v[6]=(__bf16)0.f; v[7]=(__bf16)0.f;
            } else {
                #pragma unroll
                for (int j = 0; j < 8; ++j) v[j] = (__bf16)0.f;
            }
            *(bf16x8*)&pa.hh_bf[(size_t)r * 320 + col] = v;
        }
    } else if (vb < 1024) {
        const int q = vb - 512;
        for (int idx = tid; idx < 8 * 64; idx += 256) {
            int r   = q * 8 + (idx >> 6);
            int col = (idx & 63) * 8;
            float4 f0 = *(const float4*)&pa.h_tail[(size_t)r * 512 + col];
            float4 f1 = *(const float4*)&pa.h_tail[(size_t)r * 512 + col + 4];
            bf16x8 v;
            v[0]=(__bf16)f0.x; v[1]=(__bf16)f0.y; v[2]=(__bf16)f0.z; v[3]=(__bf16)f0.w;
            v[4]=(__bf16)f1.x; v[5]=(__bf16)f1.y; v[6]=(__bf16)f1.z; v[7]=(__bf16)f1.w;
            *(bf16x8*)&pa.ht_bf[(size_t)r * 512 + col] = v;
        }
    } else if (vb < 1060) {
        const int i = vb - 1024;
        const int f = i / 12, t = i % 12;
        fold_tile(pa.qkvw[f], pa.map_w, pa.map_b, pa.F[f], t % 3, t / 3, SMEM);
    } else {
        const int i  = vb - 1060;
        const int jz = i >> 6;
        const int q  = i & 63;
        typedef __bf16 trow[72];
        trow* T = (trow*)SMEM;
        const float* src = pa.tsrc[jz];
        __bf16* dst = pa.tdst[jz];
        const int tk = (q >> 3) * 64;
        const int tn = (q & 7) * 64;
        const int r0 = tid >> 4;
        const int c0 = (tid & 15) * 4;
        #pragma unroll
        for (int ii = 0; ii < 4; ++ii) {
            float4 v = *(const float4*)&src[(size_t)(tk + r0 + ii * 16) * 512 + tn + c0];
            T[r0 + ii * 16][c0 + 0] = (__bf16)v.x;
            T[r0 + ii * 16][c0 + 1] = (__bf16)v.y;
            T[r0 + ii * 16][c0 + 2] = (__bf16)v.z;
            T[r0 + ii * 16][c0 + 3] = (__bf16)v.w;
        }
        __syncthreads();
        const int n  = tid >> 2;
        const int kk = (tid & 3) * 16;
        bf16x8 o0, o1;
        #pragma unroll
        for (int j = 0; j < 8; ++j) { o0[j] = T[kk + j][n]; o1[j] = T[kk + 8 + j][n]; }
        __bf16* dp = dst + (size_t)(tn + n) * 512 + tk + kk;
        *(bf16x8*)dp       = o0;
        *(bf16x8*)(dp + 8) = o1;
    }
}

// ------------------------------ GEMM 128x128 -------------------------------
// C = A[M,Kp]bf16 @ W[N,Kp]bf16^T + bias; z = job select. Main loop
// byte-identical to round 7 (double-buffered global_load_lds + XOR swizzle).
struct GemmJobs {
    const __bf16* A[6];
    const __bf16* W[6];
    const float*  bias[6];
    void*         C[6];
    int           Kp[6];
};

template <typename TC>
__global__ __launch_bounds__(256) void gemm128(GemmJobs jobs) {
    __shared__ __align__(16) __bf16 As[2][4096];   // 2 x [128][32]
    __shared__ __align__(16) __bf16 Bs[2][4096];

    const int z = blockIdx.z;
    const __bf16* A    = jobs.A[z];
    const __bf16* W    = jobs.W[z];
    const float*  bias = jobs.bias[z];
    TC*           C    = (TC*)jobs.C[z];
    const int     Kp   = jobs.Kp[z];

    const int tid  = threadIdx.x;
    const int wave = tid >> 6;
    const int lane = tid & 63;
    const int quad = lane >> 4;
    const int l16  = lane & 15;
    const int wy   = wave >> 1;
    const int wx   = wave & 1;
    const int rowBase = blockIdx.y * 128;
    const int colBase = blockIdx.x * 128;

    const int s_row = tid >> 2;
    const int s_kc  = ((tid & 3) ^ ((s_row >> 1) & 3)) * 8;

    const __bf16* gA = A + (size_t)(rowBase + s_row) * Kp + s_kc;
    const __bf16* gB = W + (size_t)(colBase + s_row) * Kp + s_kc;
    const int waveOff = wave * 512;

    f32x4 acc[4][4] = {};
    const int nk = Kp >> 5;

    __builtin_amdgcn_global_load_lds(AS1(gA),                   AS3(&As[0][waveOff]),        16, 0, 0);
    __builtin_amdgcn_global_load_lds(AS1(gA + (size_t)64 * Kp), AS3(&As[0][2048 + waveOff]), 16, 0, 0);
    __builtin_amdgcn_global_load_lds(AS1(gB),                   AS3(&Bs[0][waveOff]),        16, 0, 0);
    __builtin_amdgcn_global_load_lds(AS1(gB + (size_t)64 * Kp), AS3(&Bs[0][2048 + waveOff]), 16, 0, 0);

    for (int i = 0; i < nk; ++i) {
        const int cur = i & 1;
        __syncthreads();   // drains tile i's loads; prev reads of buf[cur^1] done

        if (i + 1 < nk) {  // issue tile i+1 into the other buffer
            const int kt = (i + 1) * 32;
            const int nx = cur ^ 1;
            __builtin_amdgcn_global_load_lds(AS1(gA + kt),                   AS3(&As[nx][waveOff]),        16, 0, 0);
            __builtin_amdgcn_global_load_lds(AS1(gA + kt + (size_t)64 * Kp), AS3(&As[nx][2048 + waveOff]), 16, 0, 0);
            __builtin_amdgcn_global_load_lds(AS1(gB + kt),                   AS3(&Bs[nx][waveOff]),        16, 0, 0);
            __builtin_amdgcn_global_load_lds(AS1(gB + kt + (size_t)64 * Kp), AS3(&Bs[nx][2048 + waveOff]), 16, 0, 0);
        }

        bf16x8 ar[4], br[4];
        #pragma unroll
        for (int ii = 0; ii < 4; ++ii) {
            const int ra = wy * 64 + ii * 16 + l16;
            ar[ii] = *(const bf16x8*)&As[cur][ra * 32 + ((quad ^ ((ra >> 1) & 3)) << 3)];
        }
        #pragma unroll
        for (int jj = 0; jj < 4; ++jj) {
            const int rb = wx * 64 + jj * 16 + l16;
            br[jj] = *(const bf16x8*)&Bs[cur][rb * 32 + ((quad ^ ((rb >> 1) & 3)) << 3)];
        }
        #pragma unroll
        for (int ii = 0; ii < 4; ++ii)
            #pragma unroll
            for (int jj = 0; jj < 4; ++jj)
                acc[ii][jj] = __builtin_amdgcn_mfma_f32_16x16x32_bf16(ar[ii], br[jj], acc[ii][jj], 0, 0, 0);
    }

    // epilogue: C/D layout col=l16, row=quad*4+reg
    #pragma unroll
    for (int jj = 0; jj < 4; ++jj) {
        int col = colBase + wx * 64 + jj * 16 + l16;
        float bv = bias[col];
        #pragma unroll
        for (int ii = 0; ii < 4; ++ii) {
            #pragma unroll
            for (int r = 0; r < 4; ++r) {
                int row = rowBase + wy * 64 + ii * 16 + quad * 4 + r;
                C[(size_t)row * HID + col] = (TC)(acc[ii][jj][r] + bv);
            }
        }
    }
}

// ------------------------- MFMA flash attention ----------------------------
// grid = (head 8, batch 64, side 2). side 0: head-q x tail-k; side 1: swap.
__global__ __launch_bounds__(256) void attn_mfma(
    const __bf16* __restrict__ Q0, const __bf16* __restrict__ K0,
    const __bf16* __restrict__ Vr0, const __bf16* __restrict__ Vc0,
    const __bf16* __restrict__ Q1, const __bf16* __restrict__ K1,
    const __bf16* __restrict__ Vr1, const __bf16* __restrict__ Vc1,
    const int* __restrict__ ranges,
    __bf16* __restrict__ O0, __bf16* __restrict__ O1,
    int Nq, int Nk)
{
    __shared__ __align__(16) __bf16 Qs[64][72];
    __shared__ __align__(16) __bf16 Ks[64][72];
    __shared__ __align__(16) __bf16 Vt[64][72];   // [dim][key]
    __shared__ __align__(16) __bf16 Ps[64][72];   // [query][key]

    const int z = blockIdx.z;
    const __bf16* Q    = z ? Q1 : Q0;
    const __bf16* Kg   = z ? K1 : K0;
    const __bf16* Vres = z ? Vr1 : Vr0;
    const __bf16* Vctx = z ? Vc1 : Vc0;
    __bf16* Out        = z ? O1 : O0;
    const int* qstart  = z ? ranges + 128 : ranges;
    const int* qend    = z ? ranges + 192 : ranges + 64;
    const int* kstart  = z ? ranges       : ranges + 128;
    const int* kend    = z ? ranges + 64  : ranges + 192;

    const int h = blockIdx.x, b = blockIdx.y;
    const int qs = qstart[b], qe = qend[b];
    const int ts = kstart[b], te = kend[b];
    const int nq = qe - qs, nk = te - ts;
    if (nq <= 0) return;

    const int tid  = threadIdx.x;
    const int wave = tid >> 6;
    const int lane = tid & 63;
    const int quad = lane >> 4;
    const int l16  = lane & 15;
    const int srow = tid >> 2;
    const int scol = (tid & 3) * 16;

    if (nk <= 0) {
        float* meanv = (float*)Qs;
        if (tid < 64) {
            float s = 0.f;
            for (int m = 0; m < Nk; ++m)
                s += (float)Vctx[(size_t)m * HID + h * 64 + tid];
            meanv[tid] = s / (float)Nk;
        }
        __syncthreads();
        int d = tid & 63;
        for (int r = qs + (tid >> 6); r < qe; r += 4) {
            size_t off = (size_t)r * HID + h * 64 + d;
            Out[off] = (__bf16)((float)Vres[off] + meanv[d]);
        }
        return;
    }

    for (int qc = 0; qc < nq; qc += 64) {
        __syncthreads();
        {
            int qg = min(qs + qc + srow, Nq - 1);
            const __bf16* src = Q + (size_t)qg * HID + h * 64 + scol;
            *(bf16x8*)&Qs[srow][scol]     = *(const bf16x8*)src;
            *(bf16x8*)&Qs[srow][scol + 8] = *(const bf16x8*)(src + 8);
        }
        __syncthreads();
        bf16x8 aq0 = *(const bf16x8*)&Qs[wave * 16 + l16][quad * 8];
        bf16x8 aq1 = *(const bf16x8*)&Qs[wave * 16 + l16][32 + quad * 8];

        f32x4 O[4] = {};
        float Mx[4], L[4];
        #pragma unroll
        for (int r = 0; r < 4; ++r) { Mx[r] = -__builtin_inff(); L[r] = 0.f; }

        for (int kc = 0; kc < nk; kc += 64) {
            __syncthreads();
            {
                int kg = min(ts + kc + srow, Nk - 1);
                const __bf16* ksrc = Kg + (size_t)kg * HID + h * 64 + scol;
                *(bf16x8*)&Ks[srow][scol]     = *(const bf16x8*)ksrc;
                *(bf16x8*)&Ks[srow][scol + 8] = *(const bf16x8*)(ksrc + 8);
                const __bf16* vsrc = Vctx + (size_t)kg * HID + h * 64 + scol;
                bf16x8 v0 = *(const bf16x8*)vsrc;
                bf16x8 v1 = *(const bf16x8*)(vsrc + 8);
                #pragma unroll
                for (int j = 0; j < 8; ++j) {
                    Vt[scol + j][srow]     = v0[j];
                    Vt[scol + 8 + j][srow] = v1[j];
                }
            }
            __syncthreads();

            f32x4 S[4] = {};
            #pragma unroll
            for (int c = 0; c < 4; ++c) {
                bf16x8 bk0 = *(const bf16x8*)&Ks[c * 16 + l16][quad * 8];
                bf16x8 bk1 = *(const bf16x8*)&Ks[c * 16 + l16][32 + quad * 8];
                S[c] = __builtin_amdgcn_mfma_f32_16x16x32_bf16(aq0, bk0, S[c], 0, 0, 0);
                S[c] = __builtin_amdgcn_mfma_f32_16x16x32_bf16(aq1, bk1, S[c], 0, 0, 0);
            }

            #pragma unroll
            for (int c = 0; c < 4; ++c) {
                bool valid = (ts + kc + c * 16 + l16) < te;
                #pragma unroll
                for (int r = 0; r < 4; ++r)
                    S[c][r] = valid ? S[c][r] * 0.125f : -__builtin_inff();
            }

            float cm[4], ps[4], alpha[4];
            #pragma unroll
            for (int r = 0; r < 4; ++r) {
                float v = fmaxf(fmaxf(S[0][r], S[1][r]), fmaxf(S[2][r], S[3][r]));
                v = fmaxf(v, __shfl_xor(v, 1, 64));
                v = fmaxf(v, __shfl_xor(v, 2, 64));
                v = fmaxf(v, __shfl_xor(v, 4, 64));
                v = fmaxf(v, __shfl_xor(v, 8, 64));
                cm[r] = v;
            }
            #pragma unroll
            for (int r = 0; r < 4; ++r) {
                float nM = fmaxf(Mx[r], cm[r]);
                alpha[r] = __expf(Mx[r] - nM);
                Mx[r] = nM;
                ps[r] = 0.f;
            }
            #pragma unroll
            for (int c = 0; c < 4; ++c)
                #pragma unroll
                for (int r = 0; r < 4; ++r) {
                    float p = __expf(S[c][r] - Mx[r]);
                    S[c][r] = p;
                    ps[r] += p;
                }
            #pragma unroll
            for (int r = 0; r < 4; ++r) {
                float v = ps[r];
                v += __shfl_xor(v, 1, 64);
                v += __shfl_xor(v, 2, 64);
                v += __shfl_xor(v, 4, 64);
                v += __shfl_xor(v, 8, 64);
                L[r] = L[r] * alpha[r] + v;
            }
            #pragma unroll
            for (int c = 0; c < 4; ++c)
                #pragma unroll
                for (int r = 0; r < 4; ++r)
                    O[c][r] *= alpha[r];

            #pragma unroll
            for (int c = 0; c < 4; ++c)
                #pragma unroll
                for (int r = 0; r < 4; ++r)
                    Ps[wave * 16 + quad * 4 + r][c * 16 + l16] = (__bf16)S[c][r];
            __syncthreads();

            bf16x8 ap0 = *(const bf16x8*)&Ps[wave * 16 + l16][quad * 8];
            bf16x8 ap1 = *(const bf16x8*)&Ps[wave * 16 + l16][32 + quad * 8];
            #pragma unroll
            for (int c = 0; c < 4; ++c) {
                bf16x8 bv0 = *(const bf16x8*)&Vt[c * 16 + l16][quad * 8];
                bf16x8 bv1 = *(const bf16x8*)&Vt[c * 16 + l16][32 + quad * 8];
                O[c] = __builtin_amdgcn_mfma_f32_16x16x32_bf16(ap0, bv0, O[c], 0, 0, 0);
                O[c] = __builtin_amdgcn_mfma_f32_16x16x32_bf16(ap1, bv1, O[c], 0, 0, 0);
            }
        }

        #pragma unroll
        for (int c = 0; c < 4; ++c) {
            int d = h * 64 + c * 16 + l16;
            #pragma unroll
            for (int r = 0; r < 4; ++r) {
                int qrow = qs + qc + wave * 16 + quad * 4 + r;
                if (qrow < qe) {
                    size_t off = (size_t)qrow * HID + d;
                    Out[off] = (__bf16)((float)Vres[off] + O[c][r] / L[r]);
                }
            }
        }
    }
}

// ------------------------------ launcher -----------------------------------
extern "C" void kernel_launch(void* const* d_in, const int* in_sizes, int n_in,
                              void* d_out, int out_size, void* d_ws, size_t ws_size,
                              hipStream_t stream) {
    (void)in_sizes; (void)n_in; (void)out_size; (void)ws_size;

    const float* h_head = (const float*)d_in[0];
    const float* h_tail = (const float*)d_in[1];
    const int* batch_head = (const int*)d_in[2];
    const int* batch_tail = (const int*)d_in[3];
    const float* map_w = (const float*)d_in[4];
    const float* map_b = (const float*)d_in[5];
    const float* q1_w = (const float*)d_in[6];
    const float* q1_b = (const float*)d_in[7];
    const float* k1_w = (const float*)d_in[8];
    const float* k1_b = (const float*)d_in[9];
    const float* v1_w = (const float*)d_in[10];
    const float* v1_b = (const float*)d_in[11];
    const float* q2_w = (const float*)d_in[12];
    const float* q2_b = (const float*)d_in[13];
    const float* k2_w = (const float*)d_in[14];
    const float* k2_b = (const float*)d_in[15];
    const float* v2_w = (const float*)d_in[16];
    const float* v2_b = (const float*)d_in[17];
    const float* d1_w = (const float*)d_in[18];
    const float* d1_b = (const float*)d_in[19];
    const float* d2_w = (const float*)d_in[20];
    const float* d2_b = (const float*)d_in[21];

    float* out = (float*)d_out;

    const size_t SZ = (size_t)NTOK * HID;
    char* ws = (char*)d_ws;
    int* ranges   = (int*)ws;                            // 1 KB
    __bf16* hh_bf = (__bf16*)(ws + 1024);                // [4096][320]
    __bf16* ht_bf = hh_bf + (size_t)NTOK * 320;          // [4096][512]
    __bf16* q2T  = ht_bf + SZ;                           // [512][512] each
    __bf16* k2T  = q2T + 512 * 512;
    __bf16* v2T  = k2T + 512 * 512;
    __bf16* d1T  = v2T + 512 * 512;
    __bf16* d2T  = d1T + 512 * 512;
    __bf16* FqT  = d2T + 512 * 512;                      // [512][320] each
    __bf16* FkT  = FqT + 512 * 320;
    __bf16* FvT  = FkT + 512 * 320;
    __bf16* qh   = FvT + 512 * 320;                      // [4096][512] each
    __bf16* kh   = qh  + SZ;
    __bf16* vh   = kh  + SZ;
    __bf16* qt   = vh  + SZ;
    __bf16* kt   = qt  + SZ;
    __bf16* vt   = kt  + SZ;
    __bf16* ctxh = vt  + SZ;
    __bf16* ctxt = ctxh + SZ;

    // D1: all leaf work (casts, ranges, transposes, fold w/ bias row)
    PrepArgs pa;
    pa.h_head = h_head; pa.h_tail = h_tail;
    pa.bh = batch_head; pa.bt = batch_tail;
    pa.map_w = map_w; pa.map_b = map_b;
    pa.qkvw[0] = q1_w; pa.qkvw[1] = k1_w; pa.qkvw[2] = v1_w;
    const float* wsrc[5] = {q2_w, k2_w, v2_w, d1_w, d2_w};
    __bf16* wdst[5] = {q2T, k2T, v2T, d1T, d2T};
    for (int i = 0; i < 5; ++i) { pa.tsrc[i] = wsrc[i]; pa.tdst[i] = wdst[i]; }
    pa.hh_bf = hh_bf; pa.ht_bf = ht_bf;
    pa.F[0] = FqT; pa.F[1] = FkT; pa.F[2] = FvT;
    pa.ranges = ranges;
    fused_prep<<<dim3(1380), dim3(256), 0, stream>>>(pa);

    // D2: ALL 6 qkv GEMMs (head Kp=320 via folded weights + plain q/k/v1 bias)
    {
        GemmJobs j;
        j.A[0] = hh_bf; j.W[0] = FqT; j.bias[0] = q1_b; j.C[0] = qh; j.Kp[0] = 320;
        j.A[1] = hh_bf; j.W[1] = FkT; j.bias[1] = k1_b; j.C[1] = kh; j.Kp[1] = 320;
        j.A[2] = hh_bf; j.W[2] = FvT; j.bias[2] = v1_b; j.C[2] = vh; j.Kp[2] = 320;
        j.A[3] = ht_bf; j.W[3] = q2T; j.bias[3] = q2_b; j.C[3] = qt; j.Kp[3] = 512;
        j.A[4] = ht_bf; j.W[4] = k2T; j.bias[4] = k2_b; j.C[4] = kt; j.Kp[4] = 512;
        j.A[5] = ht_bf; j.W[5] = v2T; j.bias[5] = v2_b; j.C[5] = vt; j.Kp[5] = 512;
        gemm128<__bf16><<<dim3(4, 32, 6), dim3(256), 0, stream>>>(j);
    }

    // D3: attention (both sides, one dispatch)
    attn_mfma<<<dim3(8, 64, 2), dim3(256), 0, stream>>>(
        qh, kt, vh, vt,
        qt, kh, vt, vh,
        ranges, ctxh, ctxt, NTOK, NTOK);

    // D4: output projections (fp32 into d_out)
    {
        GemmJobs j;
        j.A[0] = ctxh; j.W[0] = d1T; j.bias[0] = d1_b; j.C[0] = out;      j.Kp[0] = 512;
        j.A[1] = ctxt; j.W[1] = d2T; j.bias[1] = d2_b; j.C[1] = out + SZ; j.Kp[1] = 512;
        j.A[2] = ctxt; j.W[2] = d2T; j.bias[2] = d2_b; j.C[2] = out + SZ; j.Kp[2] = 512;
        j.A[3] = ctxt; j.W[3] = d2T; j.bias[3] = d2_b; j.C[3] = out + SZ; j.Kp[3] = 512;
        j.A[4] = ctxt; j.W[4] = d2T; j.bias[4] = d2_b; j.C[4] = out + SZ; j.Kp[4] = 512;
        j.A[5] = ctxt; j.W[5] = d2T; j.bias[5] = d2_b; j.C[5] = out + SZ; j.Kp[5] = 512;
        gemm128<float><<<dim3(4, 32, 2), dim3(256), 0, stream>>>(j);
    }
}